// Round 11
// baseline (283.600 us; speedup 1.0000x reference)
//
#include <hip/hip_runtime.h>

// DiscreteKeyValueBottleneck on MI355X (gfx950)
// B=4 T=1024 H=12 C=4096 DK=DV=64, N=B*T=4096, DIM=768
//
// Pipeline (absmax=0): split-bf16 MFMA scores (xh*eh + xh*el + xl*eh), top-2
// margin filter (TAU), numpy-bit-exact fp32 re-argmin of flagged queries.
// Round 11: r10 was L2-feed-bound (1.66 GB E2T reads at ~11.3 TB/s) and the
// recheck read 790 MB of ke. Fix 1: 2 query-tiles per wave share each staged
// B-chunk (24 MFMA/chunk, 64 queries/block) -> E-traffic halves to 830 MB;
// grid 768 = exactly 3 blocks/CU. The r10-proven sync discipline is kept
// verbatim: 9-op staging groups, vmcnt(9) RAW wait, lgkmcnt(0) WAR drain
// before the overwriting prefetch, wave-private buffers, no __syncthreads in
// the K-loop. Fix 2: recheck inverted -- flags bucketed per head; each block
// stages a 128-code ke slice in LDS once (total ke read 12.6 MB) and loops
// over that head's flagged queries; (d2,c)-packed u64 atomicMin merge.

#define HEADS 12
#define CODES 4096
#define DKI   64
#define DVI   64
#define NTOK  4096
#define DIMX  768
#define TAU   5e-5f
#define WLH   1024            // worklist capacity per head
#define CHB   8448            // staged chunk bytes: 4096 hi + 4096 lo + 256 m2

typedef short bf16x8 __attribute__((ext_vector_type(8)));
typedef float f32x16 __attribute__((ext_vector_type(16)));
typedef unsigned long long u64;

__device__ __forceinline__ unsigned short f2bf(float f) {   // RNE
    unsigned int u = __float_as_uint(f);
    return (unsigned short)((u + 0x7fff + ((u >> 16) & 1)) >> 16);
}
__device__ __forceinline__ float bf2f(unsigned short h) {
    return __uint_as_float(((unsigned int)h) << 16);
}
__device__ __forceinline__ void async_load16(const void* g, void* l) {
    __builtin_amdgcn_global_load_lds(
        (const __attribute__((address_space(1))) unsigned int*)g,
        (__attribute__((address_space(3))) unsigned int*)l, 16, 0, 0);
}
__device__ __forceinline__ void async_load4(const void* g, void* l) {
    __builtin_amdgcn_global_load_lds(
        (const __attribute__((address_space(1))) unsigned int*)g,
        (__attribute__((address_space(3))) unsigned int*)l, 4, 0, 0);
}

// ---------------- numpy bit-exact helpers (fp32, contraction OFF) -----------
__device__ __forceinline__ float np_sumsq64(const float* __restrict__ a) {
#pragma clang fp contract(off)
    float r[8];
#pragma unroll
    for (int j = 0; j < 8; ++j) r[j] = a[j] * a[j];
#pragma unroll
    for (int i = 8; i < 64; i += 8)
#pragma unroll
        for (int j = 0; j < 8; ++j) r[j] += a[i + j] * a[i + j];
    return ((r[0] + r[1]) + (r[2] + r[3])) + ((r[4] + r[5]) + (r[6] + r[7]));
}

__device__ __forceinline__ float np_dot64(const float* __restrict__ xx,
                                          const float* __restrict__ ee) {
#pragma clang fp contract(off)
    float S0 = 0.f, S1 = 0.f, S2 = 0.f, S3 = 0.f;
#pragma unroll
    for (int t = 0; t < 64; t += 16) {
        float p[16];
#pragma unroll
        for (int j = 0; j < 16; ++j) p[j] = xx[t + j] * ee[t + j];
        S0 = p[0] + (p[4] + (p[8]  + (p[12] + S0)));
        S1 = p[1] + (p[5] + (p[9]  + (p[13] + S1)));
        S2 = p[2] + (p[6] + (p[10] + (p[14] + S2)));
        S3 = p[3] + (p[7] + (p[11] + (p[15] + S3)));
    }
    return (S0 + S1) + (S2 + S3);
}

// ---- prep: np-exact e2; E2T chunk layout + embedded m2 ---------------------
// Per (h, 32-code chunk), 8448B: [hi: piece p(0..7) x 32 codes x 16B]
// [lo: same] [m2: 32 floats = -0.5*e2] [pad 128B]. piece p = dims p*8..p*8+7.
__global__ __launch_bounds__(256) void prep_ke(const float* __restrict__ ke,
                                               char* __restrict__ E2T,
                                               float* __restrict__ e2np,
                                               int* __restrict__ wl_cnt) {
    if (blockIdx.x == 0 && threadIdx.x < HEADS) wl_cnt[threadIdx.x] = 0;
    int idx = blockIdx.x * 256 + threadIdx.x;
    if (idx >= HEADS * CODES) return;
    float er[DKI];
    const float4* p4 = reinterpret_cast<const float4*>(ke + (size_t)idx * DKI);
#pragma unroll
    for (int i = 0; i < DKI / 4; ++i) {
        float4 v = p4[i];
        er[i * 4 + 0] = v.x; er[i * 4 + 1] = v.y;
        er[i * 4 + 2] = v.z; er[i * 4 + 3] = v.w;
    }
    float e2 = np_sumsq64(er);
    e2np[idx] = e2;

    int h = idx >> 12, c = idx & 4095, ch = c >> 5, cc = c & 31;
    char* cb = E2T + (size_t)(h * 128 + ch) * CHB;
    uint4* hq = reinterpret_cast<uint4*>(cb);
    uint4* lq = reinterpret_cast<uint4*>(cb + 4096);
#pragma unroll
    for (int p = 0; p < 8; ++p) {
        unsigned int hb[8], lb[8];
#pragma unroll
        for (int j = 0; j < 8; ++j) {
            float f = er[p * 8 + j];
            unsigned short hh = f2bf(f);
            hb[j] = hh;
            lb[j] = f2bf(f - bf2f(hh));
        }
        uint4 hv, lv;
        hv.x = hb[0] | (hb[1] << 16); hv.y = hb[2] | (hb[3] << 16);
        hv.z = hb[4] | (hb[5] << 16); hv.w = hb[6] | (hb[7] << 16);
        lv.x = lb[0] | (lb[1] << 16); lv.y = lb[2] | (lb[3] << 16);
        lv.z = lb[4] | (lb[5] << 16); lv.w = lb[6] | (lb[7] << 16);
        hq[p * 32 + cc] = hv;
        lq[p * 32 + cc] = lv;
    }
    reinterpret_cast<float*>(cb + 8192)[cc] = -0.5f * e2;
}

// ---- pass 1: wave-private LDS staging; 2 query-tiles share each B chunk ----
__global__ __launch_bounds__(128, 2) void dkvb_mfma(const float* __restrict__ x,
                                                    const char* __restrict__ E2T,
                                                    const float* __restrict__ values,
                                                    int* __restrict__ wl_cnt,
                                                    int* __restrict__ wl,
                                                    u64* __restrict__ packed,
                                                    float* __restrict__ out) {
    __shared__ __align__(16) char lds[2][2][CHB];   // [dbuf][wave][chunk]
    __shared__ float sbv[2][64], sbv2[2][64];
    __shared__ int   sbi[2][64];
    __shared__ int   fin[64];

    const int tid  = threadIdx.x;
    const int b    = blockIdx.x;
    const int h    = b % 12;            // XCD-friendly head pinning
    const int q0   = (b / 12) * 64;     // 64 queries per block
    const int w    = tid >> 6;          // wave = code half
    const int lane = tid & 63;
    const int col  = lane & 31;         // A row m / B col n / D col
    const int kh   = lane >> 5;         // k-half within each K=16 step
    const int cbase = w * 2048;

    // ---- A fragments, 2 tiles: query q0 + ti*32 + col ----------------------
    bf16x8 ah[2][4], al[2][4];
#pragma unroll
    for (int ti = 0; ti < 2; ++ti) {
        const float* xrow = x + (size_t)(q0 + ti * 32 + col) * DIMX + h * DKI;
#pragma unroll
        for (int t = 0; t < 4; ++t) {
            const float* p = xrow + t * 16 + kh * 8;
            bf16x8 hi, lo;
#pragma unroll
            for (int j = 0; j < 8; ++j) {
                float f = p[j];
                unsigned short hb = f2bf(f);
                hi[j] = (short)hb;
                lo[j] = (short)f2bf(f - bf2f(hb));
            }
            ah[ti][t] = hi; al[ti][t] = lo;
        }
    }

    const char* gsrc0 = E2T + (size_t)(h * 128 + w * 64) * CHB;

    float bv[2][16], bv2[2][16]; int bi[2][16];
#pragma unroll
    for (int ti = 0; ti < 2; ++ti)
#pragma unroll
        for (int r = 0; r < 16; ++r) {
            bv[ti][r] = -1e30f; bv2[ti][r] = -1e30f; bi[ti][r] = 0;
        }

    // one staging group = exactly 9 global_load_lds ops (8 w16 + 1 w4)
    auto stage = [&](const char* cb, char* buf) {
#pragma unroll
        for (int k = 0; k < 8; ++k)
            async_load16(cb + k * 1024 + lane * 16, buf + k * 1024);
        async_load4(cb + 8192 + lane * 4, buf + 8192);
    };

    stage(gsrc0,       &lds[0][w][0]);
    stage(gsrc0 + CHB, &lds[1][w][0]);

    auto body = [&](char* buf, int i) {
        // RAW: chunk i landed when <=9 vmem outstanding (chunk i+1's group).
        asm volatile("s_waitcnt vmcnt(9)" ::: "memory");

        float m2v = *reinterpret_cast<const float*>(buf + 8192 + col * 4);
        bf16x8 Bh[4], Bl[4];
#pragma unroll
        for (int t = 0; t < 4; ++t) {
            int off = ((2 * t + kh) * 32 + col) * 16;
            Bh[t] = *reinterpret_cast<const bf16x8*>(buf + off);
            Bl[t] = *reinterpret_cast<const bf16x8*>(buf + 4096 + off);
        }
        // WAR: ds_read data must be IN VGPRS before the overwriting prefetch
        // is issued (asm = full sched barrier; lgkmcnt(0) = reads returned).
        asm volatile("s_waitcnt lgkmcnt(0)" ::: "memory");

        stage(gsrc0 + (size_t)(i + 2) * CHB, buf);   // E2T padded +2 chunks

        f32x16 a0, a1;
#pragma unroll
        for (int r = 0; r < 16; ++r) { a0[r] = m2v; a1[r] = m2v; }

        // two independent 12-deep chains (one per query tile), B shared
        a0 = __builtin_amdgcn_mfma_f32_32x32x16_bf16(ah[0][0], Bh[0], a0, 0, 0, 0);
        a1 = __builtin_amdgcn_mfma_f32_32x32x16_bf16(ah[1][0], Bh[0], a1, 0, 0, 0);
        a0 = __builtin_amdgcn_mfma_f32_32x32x16_bf16(ah[0][1], Bh[1], a0, 0, 0, 0);
        a1 = __builtin_amdgcn_mfma_f32_32x32x16_bf16(ah[1][1], Bh[1], a1, 0, 0, 0);
        a0 = __builtin_amdgcn_mfma_f32_32x32x16_bf16(ah[0][2], Bh[2], a0, 0, 0, 0);
        a1 = __builtin_amdgcn_mfma_f32_32x32x16_bf16(ah[1][2], Bh[2], a1, 0, 0, 0);
        a0 = __builtin_amdgcn_mfma_f32_32x32x16_bf16(ah[0][3], Bh[3], a0, 0, 0, 0);
        a1 = __builtin_amdgcn_mfma_f32_32x32x16_bf16(ah[1][3], Bh[3], a1, 0, 0, 0);
        a0 = __builtin_amdgcn_mfma_f32_32x32x16_bf16(al[0][0], Bh[0], a0, 0, 0, 0);
        a1 = __builtin_amdgcn_mfma_f32_32x32x16_bf16(al[1][0], Bh[0], a1, 0, 0, 0);
        a0 = __builtin_amdgcn_mfma_f32_32x32x16_bf16(al[0][1], Bh[1], a0, 0, 0, 0);
        a1 = __builtin_amdgcn_mfma_f32_32x32x16_bf16(al[1][1], Bh[1], a1, 0, 0, 0);
        a0 = __builtin_amdgcn_mfma_f32_32x32x16_bf16(al[0][2], Bh[2], a0, 0, 0, 0);
        a1 = __builtin_amdgcn_mfma_f32_32x32x16_bf16(al[1][2], Bh[2], a1, 0, 0, 0);
        a0 = __builtin_amdgcn_mfma_f32_32x32x16_bf16(al[0][3], Bh[3], a0, 0, 0, 0);
        a1 = __builtin_amdgcn_mfma_f32_32x32x16_bf16(al[1][3], Bh[3], a1, 0, 0, 0);
        a0 = __builtin_amdgcn_mfma_f32_32x32x16_bf16(ah[0][0], Bl[0], a0, 0, 0, 0);
        a1 = __builtin_amdgcn_mfma_f32_32x32x16_bf16(ah[1][0], Bl[0], a1, 0, 0, 0);
        a0 = __builtin_amdgcn_mfma_f32_32x32x16_bf16(ah[0][1], Bl[1], a0, 0, 0, 0);
        a1 = __builtin_amdgcn_mfma_f32_32x32x16_bf16(ah[1][1], Bl[1], a1, 0, 0, 0);
        a0 = __builtin_amdgcn_mfma_f32_32x32x16_bf16(ah[0][2], Bl[2], a0, 0, 0, 0);
        a1 = __builtin_amdgcn_mfma_f32_32x32x16_bf16(ah[1][2], Bl[2], a1, 0, 0, 0);
        a0 = __builtin_amdgcn_mfma_f32_32x32x16_bf16(ah[0][3], Bl[3], a0, 0, 0, 0);
        a1 = __builtin_amdgcn_mfma_f32_32x32x16_bf16(ah[1][3], Bl[3], a1, 0, 0, 0);

        int cc = cbase + i * 32 + col;
#pragma unroll
        for (int r = 0; r < 16; ++r) {
            float s = a0[r];
            bv2[0][r] = __builtin_amdgcn_fmed3f(bv2[0][r], s, bv[0][r]);
            bool gt = s > bv[0][r];
            bi[0][r] = gt ? cc : bi[0][r];
            bv[0][r] = fmaxf(bv[0][r], s);
        }
#pragma unroll
        for (int r = 0; r < 16; ++r) {
            float s = a1[r];
            bv2[1][r] = __builtin_amdgcn_fmed3f(bv2[1][r], s, bv[1][r]);
            bool gt = s > bv[1][r];
            bi[1][r] = gt ? cc : bi[1][r];
            bv[1][r] = fmaxf(bv[1][r], s);
        }
    };

#pragma unroll 1
    for (int i = 0; i < 64; i += 2) {
        body(&lds[0][w][0], i);
        body(&lds[1][w][0], i + 1);
    }

    // ---- cross-col top-2 butterfly (32 cols; masks 1..16 keep kh) ----------
#pragma unroll
    for (int ti = 0; ti < 2; ++ti)
#pragma unroll
        for (int r = 0; r < 16; ++r) {
#pragma unroll
            for (int m = 1; m <= 16; m <<= 1) {
                float pv1 = __shfl_xor(bv[ti][r],  m, 64);
                float pv2 = __shfl_xor(bv2[ti][r], m, 64);
                int   pi  = __shfl_xor(bi[ti][r],  m, 64);
                bool take = (pv1 > bv[ti][r]) ||
                            (pv1 == bv[ti][r] && pi < bi[ti][r]);
                float lo1 = take ? bv[ti][r] : pv1;
                bv2[ti][r] = fmaxf(lo1, fmaxf(bv2[ti][r], pv2));
                bv[ti][r]  = take ? pv1 : bv[ti][r];
                bi[ti][r]  = take ? pi  : bi[ti][r];
            }
        }
    if (col == 0) {                     // lanes 0 and 32
#pragma unroll
        for (int ti = 0; ti < 2; ++ti)
#pragma unroll
            for (int r = 0; r < 16; ++r) {
                int row = (r & 3) + 8 * (r >> 2) + 4 * kh;   // D-row
                int q = ti * 32 + row;
                sbv [w][q] = bv[ti][r];
                sbv2[w][q] = bv2[ti][r];
                sbi [w][q] = bi[ti][r];
            }
    }
    __syncthreads();

    // ---- merge halves, flag small margins into per-head bucket -------------
    if (tid < 64) {
        int q = tid;
        float bvA = sbv[0][q],  bvB = sbv[1][q];
        float b2A = sbv2[0][q], b2B = sbv2[1][q];
        bool  tb  = bvB > bvA;                    // tie -> half 0 (smaller c)
        float bvm  = tb ? bvB : bvA;
        int   bim  = tb ? sbi[1][q] : sbi[0][q];
        float bv2m = fmaxf(fmaxf(b2A, b2B), fminf(bvA, bvB));
        fin[q] = bim;
        if (bvm - bv2m < TAU) {
            int n = q0 + q;
            int slot = atomicAdd(&wl_cnt[h], 1);
            if (slot < WLH) {
                wl[h * WLH + slot] = n;
                packed[(h << 12) | n] = ~0ull;
            }
        }
    }
    __syncthreads();

    // ---- gather values[h, fin[q], :] -> out; 64 rows x 16 float4 -----------
#pragma unroll
    for (int k = 0; k < 8; ++k) {
        int f   = tid + k * 128;
        int row = f >> 4;
        int cl  = (f & 15) << 2;
        int idx = fin[row];
        float4 v = *reinterpret_cast<const float4*>(
            values + (size_t)h * CODES * DVI + (size_t)idx * DVI + cl);
        *reinterpret_cast<float4*>(
            out + (size_t)(q0 + row) * DIMX + h * DVI + cl) = v;
    }
}

// ---- pass 2a: numpy-bit-exact d2; ke slice staged in LDS once --------------
// Block (g,h) owns codes [g*128, g*128+128) of head h; loops the head's
// flagged queries. d2 > 0 -> float bits order-preserving: pack (d2_bits, c)
// in u64, atomicMin = min d2 with first-index tiebreak.
__global__ __launch_bounds__(256) void np_recheck(const float* __restrict__ x,
                                                  const float* __restrict__ ke,
                                                  const float* __restrict__ e2np,
                                                  const int* __restrict__ wl_cnt,
                                                  const int* __restrict__ wl,
                                                  u64* __restrict__ packed) {
    __shared__ float kes[128][65];     // +1 pad: conflict-free row reads
    __shared__ float xs[DKI];

    const int tid = threadIdx.x;
    const int g = blockIdx.x, h = blockIdx.y;
    const int c0 = g * 128;

#pragma unroll
    for (int i = 0; i < 32; ++i) {
        int flat = tid + i * 256;       // 8192 floats
        int row = flat >> 6, cf = flat & 63;
        kes[row][cf] = ke[((size_t)h * CODES + c0 + row) * DKI + cf];
    }
    float e2c = (tid < 128) ? e2np[h * CODES + c0 + tid] : 0.f;

    int cnt = wl_cnt[h];
    if (cnt > WLH) cnt = WLH;

    for (int e = 0; e < cnt; ++e) {
        __syncthreads();               // xs reuse guard + kes ready (e==0)
        int nq = wl[h * WLH + e];
        if (tid < DKI) xs[tid] = x[(size_t)nq * DIMX + h * DKI + tid];
        __syncthreads();

        if (tid < 128) {
            float x2 = np_sumsq64(xs);
            float dot = np_dot64(xs, &kes[tid][0]);
            float d2;
            {
#pragma clang fp contract(off)
                d2 = (x2 - 2.0f * dot) + e2c;
            }
            u64 pk = ((u64)__float_as_uint(d2) << 32) | (unsigned)(c0 + tid);
#pragma unroll
            for (int m = 1; m <= 32; m <<= 1) {
                u64 o = ((u64)__shfl_xor((int)(pk >> 32), m, 64) << 32)
                      | (unsigned)__shfl_xor((int)(pk & 0xffffffffu), m, 64);
                pk = o < pk ? o : pk;
            }
            if ((tid & 63) == 0)
                atomicMin(&packed[(h << 12) | nq], pk);
        }
    }
}

// ---- pass 2b: scatter corrected rows ---------------------------------------
__global__ __launch_bounds__(64) void np_scatter(const float* __restrict__ values,
                                                 const int* __restrict__ wl_cnt,
                                                 const int* __restrict__ wl,
                                                 const u64* __restrict__ packed,
                                                 float* __restrict__ out) {
    const int t = threadIdx.x, h = blockIdx.y;
    int cnt = wl_cnt[h];
    if (cnt > WLH) cnt = WLH;
    for (int e = blockIdx.x; e < cnt; e += gridDim.x) {
        int nq = wl[h * WLH + e];
        int c = (int)(packed[(h << 12) | nq] & 0xffffffffull);
        out[(size_t)nq * DIMX + h * DVI + t] =
            values[((size_t)h * CODES + c) * DVI + t];
    }
}

extern "C" void kernel_launch(void* const* d_in, const int* in_sizes, int n_in,
                              void* d_out, int out_size, void* d_ws, size_t ws_size,
                              hipStream_t stream) {
    const float* x      = (const float*)d_in[0];
    // d_in[1] = mask (all ones; unused)
    const float* ke     = (const float*)d_in[2];
    const float* values = (const float*)d_in[3];
    // d_in[4] = key_optim (unused)
    float* out = (float*)d_out;

    char* ws = (char*)d_ws;
    float* e2np   = (float*)ws;  ws += HEADS * CODES * sizeof(float);
    int*   wl_cnt = (int*)ws;    ws += 64;
    int*   wl     = (int*)ws;    ws += HEADS * WLH * sizeof(int);
    u64*   packed = (u64*)ws;    ws += (size_t)HEADS * NTOK * sizeof(u64);
    char*  E2T    = ws;          // (1536 + 2 pad) chunks * 8448B ~ 13.0 MB

    prep_ke<<<dim3((HEADS * CODES + 255) / 256), dim3(256), 0, stream>>>(
        ke, E2T, e2np, wl_cnt);
    dkvb_mfma<<<dim3((NTOK / 64) * HEADS), dim3(128), 0, stream>>>(
        x, E2T, values, wl_cnt, wl, packed, out);
    np_recheck<<<dim3(32, HEADS), dim3(256), 0, stream>>>(
        x, ke, e2np, wl_cnt, wl, packed);
    np_scatter<<<dim3(32, HEADS), dim3(64), 0, stream>>>(
        values, wl_cnt, wl, packed, out);
}